// Round 3
// baseline (369.488 us; speedup 1.0000x reference)
//
#include <hip/hip_runtime.h>
#include <hip/hip_bf16.h>
#include <stdint.h>

#define E_DIM 768
#define S_LEN 2048
#define BATCH 8

typedef __attribute__((ext_vector_type(8))) short short8;   // 8 x bf16 = 4 VGPRs
typedef __attribute__((ext_vector_type(4))) float floatx4;  // MFMA C/D

__device__ __forceinline__ short f2bf(float f) {
    return __builtin_bit_cast(short, __float2bfloat16(f));
}

__device__ __forceinline__ floatx4 mfma16(short8 a, short8 b, floatx4 c) {
    return __builtin_amdgcn_mfma_f32_16x16x32_bf16(a, b, c, 0, 0, 0);
}

// async global->LDS, 16B per lane; LDS dst is wave-uniform base + lane*16,
// global src per-lane free -> XOR swizzle realized by permuting the SOURCE.
__device__ __forceinline__ void glds16(const short* g, short* l) {
    __builtin_amdgcn_global_load_lds(
        (const __attribute__((address_space(1))) void*)g,
        (__attribute__((address_space(3))) void*)l,
        16, 0, 0);
}

// ---------------------------------------------------------------------------
// Shared GEMM core R7: C[128x128] += A[128xK] * B[128xK]^T, strides sA/sB.
// 256 threads = 4 waves (2x2), each wave 64x64 via 4x4 frags of 16x16x32.
//
// T3+T4 applied surgically (vs R5's failed 256^2 rewrite): BK=32, ring-3 LDS
// (3 x (8KB A + 8KB B) = 48KB -> keeps 3 blocks/CU), prefetch depth 2 via
// global_load_lds, ONE barrier per K-32 with counted s_waitcnt vmcnt(4)
// (never a full drain in steady state). Ledger: 4 glds/thread/tile; steady
// outstanding = 8 (tiles t+1,t+2); vmcnt(4) retires tile t+1. lgkmcnt(0)
// before each barrier forces ds_reads to retire before the slot is re-staged
// (slot (t+3)%3 == t%3). Ring-3 race-freedom: slot t%3 is rewritten at iter
// t+1, after the end-of-t barrier, by which time all waves' reads of it are
// retired (lgkmcnt(0)).
//
// LDS swizzle (BK=32 -> 4 x 16B units/row, 8-unit row-PAIRS): unit u of row
// r lives at granule (r>>1)*8 + (((r&1)*4+u) ^ ((r>>1)&7)). Per row-pair the
// map (sub,u) -> slot is an XOR bijection -> each 1KB span's 64 granules are
// hit exactly once per wave-read -> conflict-free ds_read_b128 (R2/R3-style;
// verify SQ_LDS_BANK_CONFLICT stays ~0). Staging keeps LDS linear and
// permutes the SOURCE address (m104/m173 discipline).
// History: R4 LDS-epilogue regressed (keep direct stores). R5 256^2/8-wave/
// 1-block-per-CU regressed 346->446 (occupancy loss + coarse phases).
// ---------------------------------------------------------------------------
__device__ __forceinline__ void gemm_core(
    const short* __restrict__ Abase, size_t sA,
    const short* __restrict__ Bbase, size_t sB,
    int K,
    short* L,                          // 3 * 8192 shorts = 48KB ring
    floatx4 acc[4][4])
{
    const int tid  = threadIdx.x;
    const int lane = tid & 63;
    const int wv   = tid >> 6;
    const int lm   = lane & 15, lq = lane >> 4;
    const int wm   = (wv & 1) * 64, wn = (wv >> 1) * 64;

    // staging geometry: thread -> (row sr, k-unit su), source-side swizzle
    const int slot8 = tid & 7;
    const int pb    = tid >> 3;              // row-pair 0..31
    const int U     = slot8 ^ (pb & 7);      // stored super-unit 0..7
    const int su    = U & 3;                 // k-unit
    const int sr    = pb * 2 + (U >> 2);     // row 0..63

    const short* ag = Abase + (size_t)sr * sA + su * 8;
    const short* bg = Bbase + (size_t)sr * sB + su * 8;
    const size_t a64 = (size_t)64 * sA, b64 = (size_t)64 * sB;
    short* dstA = L + wv * 512;              // wave-uniform; HW adds lane*16B
    short* dstB = L + 4096 + wv * 512;

    const int nt = K >> 5;                   // K-tiles of 32 (nt >= 4 here)

#define STAGE(slot, kc) {                                  \
        short* _a = dstA + (slot) * 8192;                  \
        short* _b = dstB + (slot) * 8192;                  \
        glds16(ag + (kc), _a);                             \
        glds16(ag + a64 + (kc), _a + 2048);                \
        glds16(bg + (kc), _b);                             \
        glds16(bg + b64 + (kc), _b + 2048); }

    // prologue: tiles 0,1 in flight; wait tile 0 landed (4 of 8 retire)
    STAGE(0, 0)
    STAGE(1, 32)
    asm volatile("s_waitcnt vmcnt(4)" ::: "memory");
    __builtin_amdgcn_s_barrier();

    int rs = 0, ws = 2;                      // read slot (t), write slot (t+2)
    for (int t = 0; t < nt; ++t) {
        if (t + 2 < nt) STAGE(ws, (t + 2) << 5)

        const short* ab = L + rs * 8192;
        const short* bb = ab + 4096;
        short8 af[4], bf[4];
#pragma unroll
        for (int i = 0; i < 4; ++i) {
            int r = wm + i * 16 + lm;
            af[i] = *(const short8*)&ab[((r >> 1) * 8 + ((((r & 1) << 2) | lq) ^ ((r >> 1) & 7))) * 8];
        }
#pragma unroll
        for (int j = 0; j < 4; ++j) {
            int r = wn + j * 16 + lm;
            bf[j] = *(const short8*)&bb[((r >> 1) * 8 + ((((r & 1) << 2) | lq) ^ ((r >> 1) & 7))) * 8];
        }
#pragma unroll
        for (int i = 0; i < 4; ++i)
#pragma unroll
            for (int j = 0; j < 4; ++j)
                acc[i][j] = mfma16(af[i], bf[j], acc[i][j]);

        const int rem = nt - 1 - t;
        if (rem >= 2) {
            // drain own ds_reads (slot rs is re-staged next iter) + tile t+1
            asm volatile("s_waitcnt lgkmcnt(0) vmcnt(4)" ::: "memory");
            __builtin_amdgcn_s_barrier();
        } else if (rem == 1) {
            asm volatile("s_waitcnt lgkmcnt(0) vmcnt(0)" ::: "memory");
            __builtin_amdgcn_s_barrier();
        }
        rs = (rs == 2) ? 0 : rs + 1;
        ws = (ws == 2) ? 0 : ws + 1;
    }
#undef STAGE
}

// ---------------------------------------------------------------------------
// prep: fused front-end (one dispatch replaces convert_wts + q-convert +
// mask_scan + rowsum memset). Flat grid partitioned by block ranges:
//   [0,2304):     weight fp32->bf16 (z = blk/576; Wq scaled by 1/E)
//   [2304,6400):  query fp32->bf16, 4 rows/block
//   [6400,6416):  rowsum zero (16 blocks x 4KB)
//   [6416,6424):  per-batch mask compaction -> jidx, nv, nvp
// ---------------------------------------------------------------------------
__global__ void prep(const float* __restrict__ Wv, const float* __restrict__ Wk,
                     const float* __restrict__ Wq, const float* __restrict__ Wo,
                     const float* __restrict__ query, const int* __restrict__ mask,
                     short* __restrict__ Wb, short* __restrict__ xq,
                     float* __restrict__ rowsum,
                     int* __restrict__ jidx, int* __restrict__ nv,
                     int* __restrict__ nvp)
{
    __shared__ int cnt[256];
    const int blk = blockIdx.x;
    const int t   = threadIdx.x;

    if (blk < 2304) {                       // ---- weight convert
        const int z = blk / 576;
        const float* src = (z == 0) ? Wv : (z == 1) ? Wk : (z == 2) ? Wq : Wo;
        const float scale = (z == 2) ? (1.0f / (float)E_DIM) : 1.0f;
        size_t i = ((size_t)(blk - z * 576) * 256 + t) * 4;
        float4 f = *(const float4*)(src + i);
        short4 h;
        h.x = f2bf(f.x * scale); h.y = f2bf(f.y * scale);
        h.z = f2bf(f.z * scale); h.w = f2bf(f.w * scale);
        *(short4*)(Wb + (size_t)z * E_DIM * E_DIM + i) = h;
    } else if (blk < 6400) {                // ---- query convert, 4 rows/block
        const int g0 = blk - 2304;          // 0..4095
        const size_t base = (size_t)g0 * 4 * E_DIM;   // rows are contiguous over b
#pragma unroll
        for (int p = 0; p < 3; ++p) {
            size_t i = base + ((size_t)p * 256 + t) * 4;
            float4 f = *(const float4*)(query + i);
            short4 h;
            h.x = f2bf(f.x); h.y = f2bf(f.y); h.z = f2bf(f.z); h.w = f2bf(f.w);
            *(short4*)(xq + i) = h;
        }
    } else if (blk < 6416) {                // ---- rowsum zero
        const int g0 = blk - 6400;
        *(float4*)(rowsum + ((size_t)g0 * 256 + t) * 4) = (float4){0.f, 0.f, 0.f, 0.f};
    } else {                                // ---- mask compaction
        const int b = blk - 6416;
        int m[8];
        int c = 0;
#pragma unroll
        for (int k = 0; k < 8; ++k) {
            m[k] = mask[b * S_LEN + t * 8 + k];
            c += (m[k] != 0);
        }
        cnt[t] = c;
        __syncthreads();
        for (int off = 1; off < 256; off <<= 1) {
            int v = (t >= off) ? cnt[t - off] : 0;
            __syncthreads();
            cnt[t] += v;
            __syncthreads();
        }
        int pos = cnt[t] - c;
        const int total = cnt[255];
#pragma unroll
        for (int k = 0; k < 8; ++k)
            if (m[k] != 0) jidx[b * S_LEN + (pos++)] = t * 8 + k;
        __syncthreads();
        for (int i = total + t; i < S_LEN; i += 256) jidx[b * S_LEN + i] = 0;
        if (t == 0) {
            nv[b] = total;
            int p = (total + 127) & ~127;
            if (p < 128) p = 128;
            nvp[b] = p;
        }
    }
}

// ---------------------------------------------------------------------------
// gather+convert value/key rows through jidx (compacted). 4 rows/block.
// ---------------------------------------------------------------------------
__global__ void gather_vk(const float* __restrict__ v, const float* __restrict__ k,
                          const int* __restrict__ jidx, const int* __restrict__ nvp,
                          short* __restrict__ xv, short* __restrict__ xk) {
    const int z = blockIdx.y, b = blockIdx.z;
    const int r0 = blockIdx.x * 4;
    if (r0 >= nvp[b]) return;
    const float* src = (z == 0) ? v : k;
    short* dst = (z == 0) ? xv : xk;
    const int tid = threadIdx.x;
#pragma unroll
    for (int p = 0; p < 3; ++p) {
        int g   = p * 256 + tid;
        int row = r0 + g / 192;
        int c4  = (g % 192) * 4;
        int srow = jidx[b * S_LEN + row];
        float4 f = *(const float4*)(src + ((size_t)b * S_LEN + srow) * E_DIM + c4);
        short4 h;
        h.x = f2bf(f.x); h.y = f2bf(f.y); h.z = f2bf(f.z); h.w = f2bf(f.w);
        *(short4*)(dst + ((size_t)b * S_LEN + row) * E_DIM + c4) = h;
    }
}

// ---------------------------------------------------------------------------
// Projections (m-tiles fast in grid -> W tile shared in L2).
// z==0: V compacted -> vt[b][n][i] (transposed); z==1: K compacted; z==2: Q.
// ---------------------------------------------------------------------------
__global__ __launch_bounds__(256, 3) void proj_kernel(
    const short* __restrict__ xv, const short* __restrict__ xk, const short* __restrict__ xq,
    const short* __restrict__ Wb, const int* __restrict__ nvp,
    short* __restrict__ vt, short* __restrict__ kb, short* __restrict__ qb)
{
    const int z  = blockIdx.z;
    const int mt = blockIdx.x;
    const int n0 = blockIdx.y * 128;

    int b = 0, lm0 = 0;
    const short* X;
    if (z == 2) {
        X = xq + (size_t)mt * 128 * E_DIM;
    } else {
        b   = mt >> 4;
        lm0 = (mt & 15) * 128;
        if (lm0 >= nvp[b]) return;
        X = ((z == 0) ? xv : xk) + ((size_t)b * S_LEN + lm0) * E_DIM;
    }
    const short* W = Wb + (size_t)z * E_DIM * E_DIM + (size_t)n0 * E_DIM;

    __shared__ __align__(16) short L[3 * 8192];

    floatx4 acc[4][4];
#pragma unroll
    for (int i = 0; i < 4; ++i)
#pragma unroll
        for (int j = 0; j < 4; ++j) acc[i][j] = (floatx4){0.f, 0.f, 0.f, 0.f};

    gemm_core(X, E_DIM, W, E_DIM, E_DIM, L, acc);

    const int lane = threadIdx.x & 63, wv = threadIdx.x >> 6;
    const int lm = lane & 15, lq = lane >> 4;
    const int wm = (wv & 1) * 64, wn = (wv >> 1) * 64;

    if (z == 0) {        // vt[b][n][i]
#pragma unroll
        for (int i = 0; i < 4; ++i)
#pragma unroll
            for (int r = 0; r < 4; ++r) {
                int li = lm0 + wm + i * 16 + lq * 4 + r;
#pragma unroll
                for (int j = 0; j < 4; ++j) {
                    int n = n0 + wn + j * 16 + lm;
                    vt[((size_t)b * E_DIM + n) * S_LEN + li] = f2bf(acc[i][j][r]);
                }
            }
    } else if (z == 1) { // kb[b][i][e]
#pragma unroll
        for (int i = 0; i < 4; ++i)
#pragma unroll
            for (int r = 0; r < 4; ++r) {
                int li = lm0 + wm + i * 16 + lq * 4 + r;
#pragma unroll
                for (int j = 0; j < 4; ++j) {
                    int n = n0 + wn + j * 16 + lm;
                    kb[((size_t)b * S_LEN + li) * E_DIM + n] = f2bf(acc[i][j][r]);
                }
            }
    } else {             // qb[m][e]
#pragma unroll
        for (int i = 0; i < 4; ++i)
#pragma unroll
            for (int r = 0; r < 4; ++r) {
                int m = mt * 128 + wm + i * 16 + lq * 4 + r;
#pragma unroll
                for (int j = 0; j < 4; ++j) {
                    int n = n0 + wn + j * 16 + lm;
                    qb[(size_t)m * E_DIM + n] = f2bf(acc[i][j][r]);
                }
            }
    }
}

// ---------------------------------------------------------------------------
// S = q.k^T over compacted columns; fused exp (no max: |s|<0.5) + rowsum.
// ---------------------------------------------------------------------------
__global__ __launch_bounds__(256, 3) void score_kernel(
    const short* __restrict__ qb, const short* __restrict__ kb,
    const int* __restrict__ nv, const int* __restrict__ nvp,
    short* __restrict__ P, float* __restrict__ rowsum)
{
    const int b  = blockIdx.z;
    const int m0 = blockIdx.x * 128;
    const int n0 = blockIdx.y * 128;
    if (n0 >= nvp[b]) return;

    __shared__ __align__(16) short L[3 * 8192];

    floatx4 acc[4][4];
#pragma unroll
    for (int i = 0; i < 4; ++i)
#pragma unroll
        for (int j = 0; j < 4; ++j) acc[i][j] = (floatx4){0.f, 0.f, 0.f, 0.f};

    gemm_core(qb + ((size_t)b * S_LEN + m0) * E_DIM, E_DIM,
              kb + ((size_t)b * S_LEN + n0) * E_DIM, E_DIM, E_DIM, L, acc);

    const int lane = threadIdx.x & 63, wv = threadIdx.x >> 6;
    const int lm = lane & 15, lq = lane >> 4;
    const int wm = (wv & 1) * 64, wn = (wv >> 1) * 64;
    const int nvb = nv[b];

    float rsum[4][4];
#pragma unroll
    for (int i = 0; i < 4; ++i)
#pragma unroll
        for (int r = 0; r < 4; ++r) rsum[i][r] = 0.f;

    const size_t Pbb = (size_t)b * S_LEN * S_LEN;
#pragma unroll
    for (int j = 0; j < 4; ++j) {
        int n = n0 + wn + j * 16 + lm;
        bool valid = n < nvb;
#pragma unroll
        for (int i = 0; i < 4; ++i) {
            int mbase = m0 + wm + i * 16 + lq * 4;
#pragma unroll
            for (int r = 0; r < 4; ++r) {
                float p = valid ? __expf(acc[i][j][r]) : 0.0f;
                rsum[i][r] += p;
                P[Pbb + (size_t)(mbase + r) * S_LEN + n] = f2bf(p);
            }
        }
    }
#pragma unroll
    for (int i = 0; i < 4; ++i)
#pragma unroll
        for (int r = 0; r < 4; ++r) {
            float v = rsum[i][r];
            v += __shfl_xor(v, 1);
            v += __shfl_xor(v, 2);
            v += __shfl_xor(v, 4);
            v += __shfl_xor(v, 8);
            if (lm == 0)
                atomicAdd(&rowsum[b * S_LEN + m0 + wm + i * 16 + lq * 4 + r], v);
        }
}

// ---------------------------------------------------------------------------
// O = (P.V)/rowsum over compacted K (nvp[b]) -> abuf bf16.
// ---------------------------------------------------------------------------
__global__ __launch_bounds__(256, 3) void pv_kernel(
    const short* __restrict__ P, const short* __restrict__ vt,
    const float* __restrict__ rowsum, const int* __restrict__ nvp,
    short* __restrict__ abuf)
{
    const int b  = blockIdx.z;
    const int m0 = blockIdx.x * 128;
    const int n0 = blockIdx.y * 128;

    __shared__ __align__(16) short L[3 * 8192];

    floatx4 acc[4][4];
#pragma unroll
    for (int i = 0; i < 4; ++i)
#pragma unroll
        for (int j = 0; j < 4; ++j) acc[i][j] = (floatx4){0.f, 0.f, 0.f, 0.f};

    gemm_core(P + (size_t)b * S_LEN * S_LEN + (size_t)m0 * S_LEN, S_LEN,
              vt + ((size_t)b * E_DIM + n0) * S_LEN, S_LEN, nvp[b], L, acc);

    const int lane = threadIdx.x & 63, wv = threadIdx.x >> 6;
    const int lm = lane & 15, lq = lane >> 4;
    const int wm = (wv & 1) * 64, wn = (wv >> 1) * 64;

#pragma unroll
    for (int i = 0; i < 4; ++i) {
        int mbase = m0 + wm + i * 16 + lq * 4;
#pragma unroll
        for (int r = 0; r < 4; ++r) {
            float inv = 1.0f / rowsum[b * S_LEN + mbase + r];
            size_t ob = ((size_t)b * S_LEN + mbase + r) * E_DIM;
#pragma unroll
            for (int j = 0; j < 4; ++j) {
                int n = n0 + wn + j * 16 + lm;
                abuf[ob + n] = f2bf(acc[i][j][r] * inv);
            }
        }
    }
}

// ---------------------------------------------------------------------------
// out[m,n] = A[m,:].Wo[n,:] + bo[n]  (fp32 out). m-fast grid.
// ---------------------------------------------------------------------------
__global__ __launch_bounds__(256, 3) void out_kernel(
    const short* __restrict__ A, const short* __restrict__ W,
    const float* __restrict__ bias, float* __restrict__ Y)
{
    const int m0 = blockIdx.x * 128;
    const int n0 = blockIdx.y * 128;

    __shared__ __align__(16) short L[3 * 8192];

    floatx4 acc[4][4];
#pragma unroll
    for (int i = 0; i < 4; ++i)
#pragma unroll
        for (int j = 0; j < 4; ++j) acc[i][j] = (floatx4){0.f, 0.f, 0.f, 0.f};

    gemm_core(A + (size_t)m0 * E_DIM, E_DIM, W + (size_t)n0 * E_DIM, E_DIM,
              E_DIM, L, acc);

    const int lane = threadIdx.x & 63, wv = threadIdx.x >> 6;
    const int lm = lane & 15, lq = lane >> 4;
    const int wm = (wv & 1) * 64, wn = (wv >> 1) * 64;

#pragma unroll
    for (int j = 0; j < 4; ++j) {
        int n = n0 + wn + j * 16 + lm;
        float bv = bias[n];
#pragma unroll
        for (int i = 0; i < 4; ++i)
#pragma unroll
            for (int r = 0; r < 4; ++r) {
                int m = m0 + wm + i * 16 + lq * 4 + r;
                Y[(size_t)m * E_DIM + n] = acc[i][j][r] + bv;
            }
    }
}

// ---------------------------------------------------------------------------
extern "C" void kernel_launch(void* const* d_in, const int* in_sizes, int n_in,
                              void* d_out, int out_size, void* d_ws, size_t ws_size,
                              hipStream_t stream) {
    const float* value = (const float*)d_in[0];
    const float* key   = (const float*)d_in[1];
    const float* query = (const float*)d_in[2];
    const int*   mask  = (const int*)d_in[3];
    const float* Wv    = (const float*)d_in[4];
    const float* Wk    = (const float*)d_in[5];
    const float* Wq    = (const float*)d_in[6];
    const float* Wo    = (const float*)d_in[7];
    const float* bo    = (const float*)d_in[8];
    float* out = (float*)d_out;

    const size_t WN  = (size_t)E_DIM * E_DIM;
    const size_t ACT = (size_t)BATCH * S_LEN * E_DIM;

    short* Wb  = (short*)d_ws;
    short* xv  = Wb + 4 * WN;
    short* xk  = xv + ACT;
    short* xq  = xk + ACT;
    short* vt  = xq + ACT;
    short* kb  = vt + ACT;
    short* qb  = kb + ACT;
    float* rowsum = (float*)(qb + ACT);
    int*   nv  = (int*)(rowsum + (size_t)BATCH * S_LEN);
    int*   nvp = nv + BATCH;
    int*   jidx = (int*)qb;            // consumed by gather before proj writes qb
    short* P    = xv;                  // overlays dead xv/xk
    short* abuf = qb;                  // overlays dead qb

    // 6 dispatches total (was 9): prep fuses wconv+qconv+mask_scan+memset.
    prep<<<6424, 256, 0, stream>>>(Wv, Wk, Wq, Wo, query, mask,
                                   Wb, xq, rowsum, jidx, nv, nvp);

    gather_vk<<<dim3(512, 2, 8), 256, 0, stream>>>(value, key, jidx, nvp, xv, xk);

    proj_kernel<<<dim3(128, 6, 3), 256, 0, stream>>>(xv, xk, xq, Wb, nvp,
                                                     vt, kb, qb);

    score_kernel<<<dim3(16, 16, 8), 256, 0, stream>>>(qb, kb, nv, nvp, P, rowsum);

    pv_kernel<<<dim3(16, 6, 8), 256, 0, stream>>>(P, vt, rowsum, nvp, abuf);

    out_kernel<<<dim3(128, 6), 256, 0, stream>>>(abuf, Wb + 3 * WN, bo, out);
}

// Round 4
// 361.211 us; speedup vs baseline: 1.0229x; 1.0229x over previous
//
#include <hip/hip_runtime.h>
#include <hip/hip_bf16.h>
#include <stdint.h>

#define E_DIM 768
#define S_LEN 2048
#define BATCH 8

typedef __attribute__((ext_vector_type(8))) short short8;   // 8 x bf16 = 4 VGPRs
typedef __attribute__((ext_vector_type(4))) float floatx4;  // MFMA C/D

__device__ __forceinline__ short f2bf(float f) {
    return __builtin_bit_cast(short, __float2bfloat16(f));
}

__device__ __forceinline__ floatx4 mfma16(short8 a, short8 b, floatx4 c) {
    return __builtin_amdgcn_mfma_f32_16x16x32_bf16(a, b, c, 0, 0, 0);
}

// async global->LDS, 16B per lane; LDS dst is wave-uniform base + lane*16,
// global src per-lane free -> XOR swizzle realized by permuting the SOURCE.
__device__ __forceinline__ void glds16(const short* g, short* l) {
    __builtin_amdgcn_global_load_lds(
        (const __attribute__((address_space(1))) void*)g,
        (__attribute__((address_space(3))) void*)l,
        16, 0, 0);
}

// ---------------------------------------------------------------------------
// Shared GEMM core R8: C[128x128] += A[128xK] * B[128xK]^T, strides sA/sB.
// 128 threads = 2 waves; wave wv computes rows [wv*64, wv*64+64) x all 128
// cols: acc[4][8] frags of 16x16x32.
//
// WHY (R8 pipe arithmetic): per CU per K-64, old 4-wave 2x2 grid moved
// 288KB through the LDS pipe (96KB stage-writes + 192KB frag-reads, A and B
// each read by 2 waves) vs 466 MFMA-cyc -> LDS-BW-bound, MfmaUtil ceiling
// ~21% (measured 24%). 2-wave/64x128 kills A-read duplication: 80KB per
// block per K-step (-17% LDS bytes/FLOP) and 5 blocks/CU (5 x 32KB = 160KB)
// -> 5 independent barrier groups.
// History: R4 LDS-epilogue regressed (keep direct stores). R5 256^2/8-wave/
// ring-4 regressed 346->446 (1 block/CU, coarse phases). R7 ring-3/BK=32/
// counted-vmcnt regressed 351->369 (2x barriers, +13MB prefetch overfetch).
// Schedule is now FROZEN at 2-barrier BK=64; only data-movement geometry
// changes from here.
// ---------------------------------------------------------------------------
__device__ __forceinline__ void gemm_core(
    const short* __restrict__ Abase, size_t sA,
    const short* __restrict__ Bbase, size_t sB,
    int K,
    short* At, short* Bt,              // 128*64 shorts each (16KB)
    floatx4 acc[4][8])
{
    const int tid  = threadIdx.x;
    const int lane = tid & 63;
    const int wv   = tid >> 6;                  // 0..1
    const int lm   = lane & 15, lq = lane >> 4;
    const int rl   = lane >> 3, sl = lane & 7;
    const int usw  = sl ^ rl;                   // swizzled source unit
    const int wm   = wv * 64;

    // wave wv stages rows [wv*64, wv*64+64): row = wv*64 + rl + 8c, c=0..7
    const short* ag = Abase + (size_t)(wv * 64 + rl) * sA + usw * 8;
    const short* bg = Bbase + (size_t)(wv * 64 + rl) * sB + usw * 8;
    short* al = At + wv * 4096;                 // row-groups wv*8 .. wv*8+7
    short* bl = Bt + wv * 4096;
    const size_t askip = 8 * sA, bskip = 8 * sB;

    for (int kt = 0; kt < K; kt += 64) {
#pragma unroll
        for (int c = 0; c < 8; ++c) glds16(ag + c * askip + kt, al + c * 512);
#pragma unroll
        for (int c = 0; c < 8; ++c) glds16(bg + c * bskip + kt, bl + c * 512);
        __syncthreads();

#pragma unroll
        for (int s = 0; s < 2; ++s) {
            const int u = s * 4 + lq;
            short8 af[4], bf[8];
#pragma unroll
            for (int i = 0; i < 4; ++i) {
                int r = wm + i * 16 + lm;
                af[i] = *(const short8*)&At[((r >> 3) * 64 + (r & 7) * 8 + (u ^ (r & 7))) * 8];
            }
#pragma unroll
            for (int j = 0; j < 8; ++j) {
                int r = j * 16 + lm;
                bf[j] = *(const short8*)&Bt[((r >> 3) * 64 + (r & 7) * 8 + (u ^ (r & 7))) * 8];
            }
#pragma unroll
            for (int i = 0; i < 4; ++i)
#pragma unroll
                for (int j = 0; j < 8; ++j)
                    acc[i][j] = mfma16(af[i], bf[j], acc[i][j]);
        }
        __syncthreads();
    }
}

// ---------------------------------------------------------------------------
// prep: fused front-end (one dispatch replaces convert_wts + q-convert +
// mask_scan + rowsum memset). Flat grid partitioned by block ranges:
//   [0,2304):     weight fp32->bf16 (z = blk/576; Wq scaled by 1/E)
//   [2304,6400):  query fp32->bf16, 4 rows/block
//   [6400,6416):  rowsum zero (16 blocks x 4KB)
//   [6416,6424):  per-batch mask compaction -> jidx, nv, nvp
// ---------------------------------------------------------------------------
__global__ void prep(const float* __restrict__ Wv, const float* __restrict__ Wk,
                     const float* __restrict__ Wq, const float* __restrict__ Wo,
                     const float* __restrict__ query, const int* __restrict__ mask,
                     short* __restrict__ Wb, short* __restrict__ xq,
                     float* __restrict__ rowsum,
                     int* __restrict__ jidx, int* __restrict__ nv,
                     int* __restrict__ nvp)
{
    __shared__ int cnt[256];
    const int blk = blockIdx.x;
    const int t   = threadIdx.x;

    if (blk < 2304) {                       // ---- weight convert
        const int z = blk / 576;
        const float* src = (z == 0) ? Wv : (z == 1) ? Wk : (z == 2) ? Wq : Wo;
        const float scale = (z == 2) ? (1.0f / (float)E_DIM) : 1.0f;
        size_t i = ((size_t)(blk - z * 576) * 256 + t) * 4;
        float4 f = *(const float4*)(src + i);
        short4 h;
        h.x = f2bf(f.x * scale); h.y = f2bf(f.y * scale);
        h.z = f2bf(f.z * scale); h.w = f2bf(f.w * scale);
        *(short4*)(Wb + (size_t)z * E_DIM * E_DIM + i) = h;
    } else if (blk < 6400) {                // ---- query convert, 4 rows/block
        const int g0 = blk - 2304;          // 0..4095
        const size_t base = (size_t)g0 * 4 * E_DIM;   // rows are contiguous over b
#pragma unroll
        for (int p = 0; p < 3; ++p) {
            size_t i = base + ((size_t)p * 256 + t) * 4;
            float4 f = *(const float4*)(query + i);
            short4 h;
            h.x = f2bf(f.x); h.y = f2bf(f.y); h.z = f2bf(f.z); h.w = f2bf(f.w);
            *(short4*)(xq + i) = h;
        }
    } else if (blk < 6416) {                // ---- rowsum zero
        const int g0 = blk - 6400;
        *(float4*)(rowsum + ((size_t)g0 * 256 + t) * 4) = (float4){0.f, 0.f, 0.f, 0.f};
    } else {                                // ---- mask compaction
        const int b = blk - 6416;
        int m[8];
        int c = 0;
#pragma unroll
        for (int k = 0; k < 8; ++k) {
            m[k] = mask[b * S_LEN + t * 8 + k];
            c += (m[k] != 0);
        }
        cnt[t] = c;
        __syncthreads();
        for (int off = 1; off < 256; off <<= 1) {
            int v = (t >= off) ? cnt[t - off] : 0;
            __syncthreads();
            cnt[t] += v;
            __syncthreads();
        }
        int pos = cnt[t] - c;
        const int total = cnt[255];
#pragma unroll
        for (int k = 0; k < 8; ++k)
            if (m[k] != 0) jidx[b * S_LEN + (pos++)] = t * 8 + k;
        __syncthreads();
        for (int i = total + t; i < S_LEN; i += 256) jidx[b * S_LEN + i] = 0;
        if (t == 0) {
            nv[b] = total;
            int p = (total + 127) & ~127;
            if (p < 128) p = 128;
            nvp[b] = p;
        }
    }
}

// ---------------------------------------------------------------------------
// gather+convert value/key rows through jidx (compacted). 4 rows/block.
// ---------------------------------------------------------------------------
__global__ void gather_vk(const float* __restrict__ v, const float* __restrict__ k,
                          const int* __restrict__ jidx, const int* __restrict__ nvp,
                          short* __restrict__ xv, short* __restrict__ xk) {
    const int z = blockIdx.y, b = blockIdx.z;
    const int r0 = blockIdx.x * 4;
    if (r0 >= nvp[b]) return;
    const float* src = (z == 0) ? v : k;
    short* dst = (z == 0) ? xv : xk;
    const int tid = threadIdx.x;
#pragma unroll
    for (int p = 0; p < 3; ++p) {
        int g   = p * 256 + tid;
        int row = r0 + g / 192;
        int c4  = (g % 192) * 4;
        int srow = jidx[b * S_LEN + row];
        float4 f = *(const float4*)(src + ((size_t)b * S_LEN + srow) * E_DIM + c4);
        short4 h;
        h.x = f2bf(f.x); h.y = f2bf(f.y); h.z = f2bf(f.z); h.w = f2bf(f.w);
        *(short4*)(dst + ((size_t)b * S_LEN + row) * E_DIM + c4) = h;
    }
}

// ---------------------------------------------------------------------------
// Projections (m-tiles fast in grid -> W tile shared in L2).
// z==0: V compacted -> vt[b][n][i] (transposed); z==1: K compacted; z==2: Q.
// ---------------------------------------------------------------------------
__global__ __launch_bounds__(128, 2) void proj_kernel(
    const short* __restrict__ xv, const short* __restrict__ xk, const short* __restrict__ xq,
    const short* __restrict__ Wb, const int* __restrict__ nvp,
    short* __restrict__ vt, short* __restrict__ kb, short* __restrict__ qb)
{
    const int z  = blockIdx.z;
    const int mt = blockIdx.x;
    const int n0 = blockIdx.y * 128;

    int b = 0, lm0 = 0;
    const short* X;
    if (z == 2) {
        X = xq + (size_t)mt * 128 * E_DIM;
    } else {
        b   = mt >> 4;
        lm0 = (mt & 15) * 128;
        if (lm0 >= nvp[b]) return;
        X = ((z == 0) ? xv : xk) + ((size_t)b * S_LEN + lm0) * E_DIM;
    }
    const short* W = Wb + (size_t)z * E_DIM * E_DIM + (size_t)n0 * E_DIM;

    __shared__ __align__(16) short At[128 * 64];
    __shared__ __align__(16) short Bt[128 * 64];

    floatx4 acc[4][8];
#pragma unroll
    for (int i = 0; i < 4; ++i)
#pragma unroll
        for (int j = 0; j < 8; ++j) acc[i][j] = (floatx4){0.f, 0.f, 0.f, 0.f};

    gemm_core(X, E_DIM, W, E_DIM, E_DIM, At, Bt, acc);

    const int lane = threadIdx.x & 63, wv = threadIdx.x >> 6;
    const int lm = lane & 15, lq = lane >> 4;
    const int wm = wv * 64;

    if (z == 0) {        // vt[b][n][i]
#pragma unroll
        for (int i = 0; i < 4; ++i)
#pragma unroll
            for (int r = 0; r < 4; ++r) {
                int li = lm0 + wm + i * 16 + lq * 4 + r;
#pragma unroll
                for (int j = 0; j < 8; ++j) {
                    int n = n0 + j * 16 + lm;
                    vt[((size_t)b * E_DIM + n) * S_LEN + li] = f2bf(acc[i][j][r]);
                }
            }
    } else if (z == 1) { // kb[b][i][e]
#pragma unroll
        for (int i = 0; i < 4; ++i)
#pragma unroll
            for (int r = 0; r < 4; ++r) {
                int li = lm0 + wm + i * 16 + lq * 4 + r;
#pragma unroll
                for (int j = 0; j < 8; ++j) {
                    int n = n0 + j * 16 + lm;
                    kb[((size_t)b * S_LEN + li) * E_DIM + n] = f2bf(acc[i][j][r]);
                }
            }
    } else {             // qb[m][e]
#pragma unroll
        for (int i = 0; i < 4; ++i)
#pragma unroll
            for (int r = 0; r < 4; ++r) {
                int m = mt * 128 + wm + i * 16 + lq * 4 + r;
#pragma unroll
                for (int j = 0; j < 8; ++j) {
                    int n = n0 + j * 16 + lm;
                    qb[(size_t)m * E_DIM + n] = f2bf(acc[i][j][r]);
                }
            }
    }
}

// ---------------------------------------------------------------------------
// S = q.k^T over compacted columns; fused exp (no max: |s|<0.5) + rowsum.
// ---------------------------------------------------------------------------
__global__ __launch_bounds__(128, 2) void score_kernel(
    const short* __restrict__ qb, const short* __restrict__ kb,
    const int* __restrict__ nv, const int* __restrict__ nvp,
    short* __restrict__ P, float* __restrict__ rowsum)
{
    const int b  = blockIdx.z;
    const int m0 = blockIdx.x * 128;
    const int n0 = blockIdx.y * 128;
    if (n0 >= nvp[b]) return;

    __shared__ __align__(16) short At[128 * 64];
    __shared__ __align__(16) short Bt[128 * 64];

    floatx4 acc[4][8];
#pragma unroll
    for (int i = 0; i < 4; ++i)
#pragma unroll
        for (int j = 0; j < 8; ++j) acc[i][j] = (floatx4){0.f, 0.f, 0.f, 0.f};

    gemm_core(qb + ((size_t)b * S_LEN + m0) * E_DIM, E_DIM,
              kb + ((size_t)b * S_LEN + n0) * E_DIM, E_DIM, E_DIM, At, Bt, acc);

    const int lane = threadIdx.x & 63, wv = threadIdx.x >> 6;
    const int lm = lane & 15, lq = lane >> 4;
    const int wm = wv * 64;
    const int nvb = nv[b];

    float rsum[4][4];
#pragma unroll
    for (int i = 0; i < 4; ++i)
#pragma unroll
        for (int r = 0; r < 4; ++r) rsum[i][r] = 0.f;

    const size_t Pbb = (size_t)b * S_LEN * S_LEN;
#pragma unroll
    for (int j = 0; j < 8; ++j) {
        int n = n0 + j * 16 + lm;
        bool valid = n < nvb;
#pragma unroll
        for (int i = 0; i < 4; ++i) {
            int mbase = m0 + wm + i * 16 + lq * 4;
#pragma unroll
            for (int r = 0; r < 4; ++r) {
                float p = valid ? __expf(acc[i][j][r]) : 0.0f;
                rsum[i][r] += p;
                P[Pbb + (size_t)(mbase + r) * S_LEN + n] = f2bf(p);
            }
        }
    }
#pragma unroll
    for (int i = 0; i < 4; ++i)
#pragma unroll
        for (int r = 0; r < 4; ++r) {
            float v = rsum[i][r];
            v += __shfl_xor(v, 1);
            v += __shfl_xor(v, 2);
            v += __shfl_xor(v, 4);
            v += __shfl_xor(v, 8);
            if (lm == 0)
                atomicAdd(&rowsum[b * S_LEN + m0 + wm + i * 16 + lq * 4 + r], v);
        }
}

// ---------------------------------------------------------------------------
// O = (P.V)/rowsum over compacted K (nvp[b]) -> abuf bf16.
// ---------------------------------------------------------------------------
__global__ __launch_bounds__(128, 2) void pv_kernel(
    const short* __restrict__ P, const short* __restrict__ vt,
    const float* __restrict__ rowsum, const int* __restrict__ nvp,
    short* __restrict__ abuf)
{
    const int b  = blockIdx.z;
    const int m0 = blockIdx.x * 128;
    const int n0 = blockIdx.y * 128;

    __shared__ __align__(16) short At[128 * 64];
    __shared__ __align__(16) short Bt[128 * 64];

    floatx4 acc[4][8];
#pragma unroll
    for (int i = 0; i < 4; ++i)
#pragma unroll
        for (int j = 0; j < 8; ++j) acc[i][j] = (floatx4){0.f, 0.f, 0.f, 0.f};

    gemm_core(P + (size_t)b * S_LEN * S_LEN + (size_t)m0 * S_LEN, S_LEN,
              vt + ((size_t)b * E_DIM + n0) * S_LEN, S_LEN, nvp[b], At, Bt, acc);

    const int lane = threadIdx.x & 63, wv = threadIdx.x >> 6;
    const int lm = lane & 15, lq = lane >> 4;
    const int wm = wv * 64;

#pragma unroll
    for (int i = 0; i < 4; ++i) {
        int mbase = m0 + wm + i * 16 + lq * 4;
#pragma unroll
        for (int r = 0; r < 4; ++r) {
            float inv = 1.0f / rowsum[b * S_LEN + mbase + r];
            size_t ob = ((size_t)b * S_LEN + mbase + r) * E_DIM;
#pragma unroll
            for (int j = 0; j < 8; ++j) {
                int n = n0 + j * 16 + lm;
                abuf[ob + n] = f2bf(acc[i][j][r] * inv);
            }
        }
    }
}

// ---------------------------------------------------------------------------
// out[m,n] = A[m,:].Wo[n,:] + bo[n]  (fp32 out). m-fast grid.
// ---------------------------------------------------------------------------
__global__ __launch_bounds__(128, 2) void out_kernel(
    const short* __restrict__ A, const short* __restrict__ W,
    const float* __restrict__ bias, float* __restrict__ Y)
{
    const int m0 = blockIdx.x * 128;
    const int n0 = blockIdx.y * 128;

    __shared__ __align__(16) short At[128 * 64];
    __shared__ __align__(16) short Bt[128 * 64];

    floatx4 acc[4][8];
#pragma unroll
    for (int i = 0; i < 4; ++i)
#pragma unroll
        for (int j = 0; j < 8; ++j) acc[i][j] = (floatx4){0.f, 0.f, 0.f, 0.f};

    gemm_core(A + (size_t)m0 * E_DIM, E_DIM, W + (size_t)n0 * E_DIM, E_DIM,
              E_DIM, At, Bt, acc);

    const int lane = threadIdx.x & 63, wv = threadIdx.x >> 6;
    const int lm = lane & 15, lq = lane >> 4;
    const int wm = wv * 64;

#pragma unroll
    for (int j = 0; j < 8; ++j) {
        int n = n0 + j * 16 + lm;
        float bv = bias[n];
#pragma unroll
        for (int i = 0; i < 4; ++i)
#pragma unroll
            for (int r = 0; r < 4; ++r) {
                int m = m0 + wm + i * 16 + lq * 4 + r;
                Y[(size_t)m * E_DIM + n] = acc[i][j][r] + bv;
            }
    }
}

// ---------------------------------------------------------------------------
extern "C" void kernel_launch(void* const* d_in, const int* in_sizes, int n_in,
                              void* d_out, int out_size, void* d_ws, size_t ws_size,
                              hipStream_t stream) {
    const float* value = (const float*)d_in[0];
    const float* key   = (const float*)d_in[1];
    const float* query = (const float*)d_in[2];
    const int*   mask  = (const int*)d_in[3];
    const float* Wv    = (const float*)d_in[4];
    const float* Wk    = (const float*)d_in[5];
    const float* Wq    = (const float*)d_in[6];
    const float* Wo    = (const float*)d_in[7];
    const float* bo    = (const float*)d_in[8];
    float* out = (float*)d_out;

    const size_t WN  = (size_t)E_DIM * E_DIM;
    const size_t ACT = (size_t)BATCH * S_LEN * E_DIM;

    short* Wb  = (short*)d_ws;
    short* xv  = Wb + 4 * WN;
    short* xk  = xv + ACT;
    short* xq  = xk + ACT;
    short* vt  = xq + ACT;
    short* kb  = vt + ACT;
    short* qb  = kb + ACT;
    float* rowsum = (float*)(qb + ACT);
    int*   nv  = (int*)(rowsum + (size_t)BATCH * S_LEN);
    int*   nvp = nv + BATCH;
    int*   jidx = (int*)qb;            // consumed by gather before proj writes qb
    short* P    = xv;                  // overlays dead xv/xk
    short* abuf = qb;                  // overlays dead qb

    // 6 dispatches total: prep fuses wconv+qconv+mask_scan+memset.
    prep<<<6424, 256, 0, stream>>>(Wv, Wk, Wq, Wo, query, mask,
                                   Wb, xq, rowsum, jidx, nv, nvp);

    gather_vk<<<dim3(512, 2, 8), 256, 0, stream>>>(value, key, jidx, nvp, xv, xk);

    proj_kernel<<<dim3(128, 6, 3), 128, 0, stream>>>(xv, xk, xq, Wb, nvp,
                                                     vt, kb, qb);

    score_kernel<<<dim3(16, 16, 8), 128, 0, stream>>>(qb, kb, nv, nvp, P, rowsum);

    pv_kernel<<<dim3(16, 6, 8), 128, 0, stream>>>(P, vt, rowsum, nvp, abuf);

    out_kernel<<<dim3(128, 6), 128, 0, stream>>>(abuf, Wb + 3 * WN, bo, out);
}

// Round 6
// 346.793 us; speedup vs baseline: 1.0654x; 1.0416x over previous
//
#include <hip/hip_runtime.h>
#include <hip/hip_bf16.h>
#include <stdint.h>

#define E_DIM 768
#define S_LEN 2048
#define BATCH 8

typedef __attribute__((ext_vector_type(8))) short short8;   // 8 x bf16 = 4 VGPRs
typedef __attribute__((ext_vector_type(4))) float floatx4;  // MFMA C/D

__device__ __forceinline__ short f2bf(float f) {
    return __builtin_bit_cast(short, __float2bfloat16(f));
}

__device__ __forceinline__ floatx4 mfma16(short8 a, short8 b, floatx4 c) {
    return __builtin_amdgcn_mfma_f32_16x16x32_bf16(a, b, c, 0, 0, 0);
}

// async global->LDS, 16B per lane; LDS dst is wave-uniform base + lane*16,
// global src per-lane free -> XOR swizzle realized by permuting the SOURCE.
__device__ __forceinline__ void glds16(const short* g, short* l) {
    __builtin_amdgcn_global_load_lds(
        (const __attribute__((address_space(1))) void*)g,
        (__attribute__((address_space(3))) void*)l,
        16, 0, 0);
}

// ---------------------------------------------------------------------------
// Shared GEMM core: C[128x128] += A[128xK] * B[128xK]^T, row strides sA/sB.
// 256 threads = 4 waves (2x2), each wave 64x64 via 4x4 frags of 16x16x32.
// BK=64 single-buffered; XOR-swizzled staging -> conflict-free ds_read_b128
// (verified: SQ_LDS_BANK_CONFLICT == 0).
//
// SESSION LEDGER (do not re-attempt):
//  R4  LDS-transpose epilogue         -> REGRESSED (347->381, +22MB fetch)
//  R5  256^2/8-wave/ring-4 vmcnt(8)   -> REGRESSED (346->446, 1 blk/CU)
//  R7  BK=32/ring-3/counted vmcnt(4)  -> REGRESSED (351->369, 2x barriers)
//  R8  2-wave/64x128 (acc[4][8])      -> REGRESSED (351->361, proj 69us:
//      128 AGPR acc -> 232 unified regs -> 2 waves/SIMD cliff, occ 11%)
// Schedule + geometry are FROZEN: 2-barrier BK=64, 4-wave 2x2, 128^2 tile.
//
// R9/R10 (R9 bench was an infra failure, resubmitted unchanged):
// register-occupancy fix from R8's counter insight. VGPR_Count excludes
// AGPRs: 68 VGPR + 64 AGPR = 132 unified -> 3 waves/SIMD (3 blocks/CU,
// binding by FOUR regs; LDS would allow 5). __launch_bounds__(256,4) forces
// VGPR<=64 -> 128 unified -> 4 blocks/CU (+33% co-resident waves for the
// m114 inter-block overlap this structure depends on).
// ---------------------------------------------------------------------------
__device__ __forceinline__ void gemm_core(
    const short* __restrict__ Abase, size_t sA,
    const short* __restrict__ Bbase, size_t sB,
    int K,
    short* At, short* Bt,              // 128*64 shorts each (16KB)
    floatx4 acc[4][4])
{
    const int tid  = threadIdx.x;
    const int lane = tid & 63;
    const int wv   = tid >> 6;
    const int lm   = lane & 15, lq = lane >> 4;
    const int rl   = lane >> 3, sl = lane & 7;
    const int usw  = sl ^ rl;                   // swizzled source unit
    const int wm   = (wv & 1) * 64, wn = (wv >> 1) * 64;

    const short* ag = Abase + (size_t)(wv * 32 + rl) * sA + usw * 8;
    const short* bg = Bbase + (size_t)(wv * 32 + rl) * sB + usw * 8;
    short* al = At + wv * 4 * 512;
    short* bl = Bt + wv * 4 * 512;
    const size_t askip = 8 * sA, bskip = 8 * sB;

    for (int kt = 0; kt < K; kt += 64) {
#pragma unroll
        for (int c = 0; c < 4; ++c) glds16(ag + c * askip + kt, al + c * 512);
#pragma unroll
        for (int c = 0; c < 4; ++c) glds16(bg + c * bskip + kt, bl + c * 512);
        __syncthreads();

#pragma unroll
        for (int s = 0; s < 2; ++s) {
            const int u = s * 4 + lq;
            short8 af[4], bf[4];
#pragma unroll
            for (int i = 0; i < 4; ++i) {
                int r = wm + i * 16 + lm;
                af[i] = *(const short8*)&At[((r >> 3) * 64 + (r & 7) * 8 + (u ^ (r & 7))) * 8];
            }
#pragma unroll
            for (int j = 0; j < 4; ++j) {
                int r = wn + j * 16 + lm;
                bf[j] = *(const short8*)&Bt[((r >> 3) * 64 + (r & 7) * 8 + (u ^ (r & 7))) * 8];
            }
#pragma unroll
            for (int i = 0; i < 4; ++i)
#pragma unroll
                for (int j = 0; j < 4; ++j)
                    acc[i][j] = mfma16(af[i], bf[j], acc[i][j]);
        }
        __syncthreads();
    }
}

// ---------------------------------------------------------------------------
// prep: fused front-end (one dispatch replaces convert_wts + q-convert +
// mask_scan + rowsum memset). Flat grid partitioned by block ranges:
//   [0,2304):     weight fp32->bf16 (z = blk/576; Wq scaled by 1/E)
//   [2304,6400):  query fp32->bf16, 4 rows/block
//   [6400,6416):  rowsum zero (16 blocks x 4KB)
//   [6416,6424):  per-batch mask compaction -> jidx, nv, nvp
// ---------------------------------------------------------------------------
__global__ void prep(const float* __restrict__ Wv, const float* __restrict__ Wk,
                     const float* __restrict__ Wq, const float* __restrict__ Wo,
                     const float* __restrict__ query, const int* __restrict__ mask,
                     short* __restrict__ Wb, short* __restrict__ xq,
                     float* __restrict__ rowsum,
                     int* __restrict__ jidx, int* __restrict__ nv,
                     int* __restrict__ nvp)
{
    __shared__ int cnt[256];
    const int blk = blockIdx.x;
    const int t   = threadIdx.x;

    if (blk < 2304) {                       // ---- weight convert
        const int z = blk / 576;
        const float* src = (z == 0) ? Wv : (z == 1) ? Wk : (z == 2) ? Wq : Wo;
        const float scale = (z == 2) ? (1.0f / (float)E_DIM) : 1.0f;
        size_t i = ((size_t)(blk - z * 576) * 256 + t) * 4;
        float4 f = *(const float4*)(src + i);
        short4 h;
        h.x = f2bf(f.x * scale); h.y = f2bf(f.y * scale);
        h.z = f2bf(f.z * scale); h.w = f2bf(f.w * scale);
        *(short4*)(Wb + (size_t)z * E_DIM * E_DIM + i) = h;
    } else if (blk < 6400) {                // ---- query convert, 4 rows/block
        const int g0 = blk - 2304;          // 0..4095
        const size_t base = (size_t)g0 * 4 * E_DIM;   // rows are contiguous over b
#pragma unroll
        for (int p = 0; p < 3; ++p) {
            size_t i = base + ((size_t)p * 256 + t) * 4;
            float4 f = *(const float4*)(query + i);
            short4 h;
            h.x = f2bf(f.x); h.y = f2bf(f.y); h.z = f2bf(f.z); h.w = f2bf(f.w);
            *(short4*)(xq + i) = h;
        }
    } else if (blk < 6416) {                // ---- rowsum zero
        const int g0 = blk - 6400;
        *(float4*)(rowsum + ((size_t)g0 * 256 + t) * 4) = (float4){0.f, 0.f, 0.f, 0.f};
    } else {                                // ---- mask compaction
        const int b = blk - 6416;
        int m[8];
        int c = 0;
#pragma unroll
        for (int k = 0; k < 8; ++k) {
            m[k] = mask[b * S_LEN + t * 8 + k];
            c += (m[k] != 0);
        }
        cnt[t] = c;
        __syncthreads();
        for (int off = 1; off < 256; off <<= 1) {
            int v = (t >= off) ? cnt[t - off] : 0;
            __syncthreads();
            cnt[t] += v;
            __syncthreads();
        }
        int pos = cnt[t] - c;
        const int total = cnt[255];
#pragma unroll
        for (int k = 0; k < 8; ++k)
            if (m[k] != 0) jidx[b * S_LEN + (pos++)] = t * 8 + k;
        __syncthreads();
        for (int i = total + t; i < S_LEN; i += 256) jidx[b * S_LEN + i] = 0;
        if (t == 0) {
            nv[b] = total;
            int p = (total + 127) & ~127;
            if (p < 128) p = 128;
            nvp[b] = p;
        }
    }
}

// ---------------------------------------------------------------------------
// gather+convert value/key rows through jidx (compacted). 4 rows/block.
// ---------------------------------------------------------------------------
__global__ void gather_vk(const float* __restrict__ v, const float* __restrict__ k,
                          const int* __restrict__ jidx, const int* __restrict__ nvp,
                          short* __restrict__ xv, short* __restrict__ xk) {
    const int z = blockIdx.y, b = blockIdx.z;
    const int r0 = blockIdx.x * 4;
    if (r0 >= nvp[b]) return;
    const float* src = (z == 0) ? v : k;
    short* dst = (z == 0) ? xv : xk;
    const int tid = threadIdx.x;
#pragma unroll
    for (int p = 0; p < 3; ++p) {
        int g   = p * 256 + tid;
        int row = r0 + g / 192;
        int c4  = (g % 192) * 4;
        int srow = jidx[b * S_LEN + row];
        float4 f = *(const float4*)(src + ((size_t)b * S_LEN + srow) * E_DIM + c4);
        short4 h;
        h.x = f2bf(f.x); h.y = f2bf(f.y); h.z = f2bf(f.z); h.w = f2bf(f.w);
        *(short4*)(dst + ((size_t)b * S_LEN + row) * E_DIM + c4) = h;
    }
}

// ---------------------------------------------------------------------------
// Projections (m-tiles fast in grid -> W tile shared in L2).
// z==0: V compacted -> vt[b][n][i] (transposed); z==1: K compacted; z==2: Q.
// ---------------------------------------------------------------------------
__global__ __launch_bounds__(256, 4) void proj_kernel(
    const short* __restrict__ xv, const short* __restrict__ xk, const short* __restrict__ xq,
    const short* __restrict__ Wb, const int* __restrict__ nvp,
    short* __restrict__ vt, short* __restrict__ kb, short* __restrict__ qb)
{
    const int z  = blockIdx.z;
    const int mt = blockIdx.x;
    const int n0 = blockIdx.y * 128;

    int b = 0, lm0 = 0;
    const short* X;
    if (z == 2) {
        X = xq + (size_t)mt * 128 * E_DIM;
    } else {
        b   = mt >> 4;
        lm0 = (mt & 15) * 128;
        if (lm0 >= nvp[b]) return;
        X = ((z == 0) ? xv : xk) + ((size_t)b * S_LEN + lm0) * E_DIM;
    }
    const short* W = Wb + (size_t)z * E_DIM * E_DIM + (size_t)n0 * E_DIM;

    __shared__ short At[128 * 64];
    __shared__ short Bt[128 * 64];

    floatx4 acc[4][4];
#pragma unroll
    for (int i = 0; i < 4; ++i)
#pragma unroll
        for (int j = 0; j < 4; ++j) acc[i][j] = (floatx4){0.f, 0.f, 0.f, 0.f};

    gemm_core(X, E_DIM, W, E_DIM, E_DIM, At, Bt, acc);

    const int lane = threadIdx.x & 63, wv = threadIdx.x >> 6;
    const int lm = lane & 15, lq = lane >> 4;
    const int wm = (wv & 1) * 64, wn = (wv >> 1) * 64;

    if (z == 0) {        // vt[b][n][i]
#pragma unroll
        for (int i = 0; i < 4; ++i)
#pragma unroll
            for (int r = 0; r < 4; ++r) {
                int li = lm0 + wm + i * 16 + lq * 4 + r;
#pragma unroll
                for (int j = 0; j < 4; ++j) {
                    int n = n0 + wn + j * 16 + lm;
                    vt[((size_t)b * E_DIM + n) * S_LEN + li] = f2bf(acc[i][j][r]);
                }
            }
    } else if (z == 1) { // kb[b][i][e]
#pragma unroll
        for (int i = 0; i < 4; ++i)
#pragma unroll
            for (int r = 0; r < 4; ++r) {
                int li = lm0 + wm + i * 16 + lq * 4 + r;
#pragma unroll
                for (int j = 0; j < 4; ++j) {
                    int n = n0 + wn + j * 16 + lm;
                    kb[((size_t)b * S_LEN + li) * E_DIM + n] = f2bf(acc[i][j][r]);
                }
            }
    } else {             // qb[m][e]
#pragma unroll
        for (int i = 0; i < 4; ++i)
#pragma unroll
            for (int r = 0; r < 4; ++r) {
                int m = mt * 128 + wm + i * 16 + lq * 4 + r;
#pragma unroll
                for (int j = 0; j < 4; ++j) {
                    int n = n0 + wn + j * 16 + lm;
                    qb[(size_t)m * E_DIM + n] = f2bf(acc[i][j][r]);
                }
            }
    }
}

// ---------------------------------------------------------------------------
// S = q.k^T over compacted columns; fused exp (no max: |s|<0.5) + rowsum.
// ---------------------------------------------------------------------------
__global__ __launch_bounds__(256, 4) void score_kernel(
    const short* __restrict__ qb, const short* __restrict__ kb,
    const int* __restrict__ nv, const int* __restrict__ nvp,
    short* __restrict__ P, float* __restrict__ rowsum)
{
    const int b  = blockIdx.z;
    const int m0 = blockIdx.x * 128;
    const int n0 = blockIdx.y * 128;
    if (n0 >= nvp[b]) return;

    __shared__ short At[128 * 64];
    __shared__ short Bt[128 * 64];

    floatx4 acc[4][4];
#pragma unroll
    for (int i = 0; i < 4; ++i)
#pragma unroll
        for (int j = 0; j < 4; ++j) acc[i][j] = (floatx4){0.f, 0.f, 0.f, 0.f};

    gemm_core(qb + ((size_t)b * S_LEN + m0) * E_DIM, E_DIM,
              kb + ((size_t)b * S_LEN + n0) * E_DIM, E_DIM, E_DIM, At, Bt, acc);

    const int lane = threadIdx.x & 63, wv = threadIdx.x >> 6;
    const int lm = lane & 15, lq = lane >> 4;
    const int wm = (wv & 1) * 64, wn = (wv >> 1) * 64;
    const int nvb = nv[b];

    float rsum[4][4];
#pragma unroll
    for (int i = 0; i < 4; ++i)
#pragma unroll
        for (int r = 0; r < 4; ++r) rsum[i][r] = 0.f;

    const size_t Pbb = (size_t)b * S_LEN * S_LEN;
#pragma unroll
    for (int j = 0; j < 4; ++j) {
        int n = n0 + wn + j * 16 + lm;
        bool valid = n < nvb;
#pragma unroll
        for (int i = 0; i < 4; ++i) {
            int mbase = m0 + wm + i * 16 + lq * 4;
#pragma unroll
            for (int r = 0; r < 4; ++r) {
                float p = valid ? __expf(acc[i][j][r]) : 0.0f;
                rsum[i][r] += p;
                P[Pbb + (size_t)(mbase + r) * S_LEN + n] = f2bf(p);
            }
        }
    }
#pragma unroll
    for (int i = 0; i < 4; ++i)
#pragma unroll
        for (int r = 0; r < 4; ++r) {
            float v = rsum[i][r];
            v += __shfl_xor(v, 1);
            v += __shfl_xor(v, 2);
            v += __shfl_xor(v, 4);
            v += __shfl_xor(v, 8);
            if (lm == 0)
                atomicAdd(&rowsum[b * S_LEN + m0 + wm + i * 16 + lq * 4 + r], v);
        }
}

// ---------------------------------------------------------------------------
// O = (P.V)/rowsum over compacted K (nvp[b]) -> abuf bf16.
// ---------------------------------------------------------------------------
__global__ __launch_bounds__(256, 4) void pv_kernel(
    const short* __restrict__ P, const short* __restrict__ vt,
    const float* __restrict__ rowsum, const int* __restrict__ nvp,
    short* __restrict__ abuf)
{
    const int b  = blockIdx.z;
    const int m0 = blockIdx.x * 128;
    const int n0 = blockIdx.y * 128;

    __shared__ short At[128 * 64];
    __shared__ short Bt[128 * 64];

    floatx4 acc[4][4];
#pragma unroll
    for (int i = 0; i < 4; ++i)
#pragma unroll
        for (int j = 0; j < 4; ++j) acc[i][j] = (floatx4){0.f, 0.f, 0.f, 0.f};

    gemm_core(P + (size_t)b * S_LEN * S_LEN + (size_t)m0 * S_LEN, S_LEN,
              vt + ((size_t)b * E_DIM + n0) * S_LEN, S_LEN, nvp[b], At, Bt, acc);

    const int lane = threadIdx.x & 63, wv = threadIdx.x >> 6;
    const int lm = lane & 15, lq = lane >> 4;
    const int wm = (wv & 1) * 64, wn = (wv >> 1) * 64;

#pragma unroll
    for (int i = 0; i < 4; ++i) {
        int mbase = m0 + wm + i * 16 + lq * 4;
#pragma unroll
        for (int r = 0; r < 4; ++r) {
            float inv = 1.0f / rowsum[b * S_LEN + mbase + r];
            size_t ob = ((size_t)b * S_LEN + mbase + r) * E_DIM;
#pragma unroll
            for (int j = 0; j < 4; ++j) {
                int n = n0 + wn + j * 16 + lm;
                abuf[ob + n] = f2bf(acc[i][j][r] * inv);
            }
        }
    }
}

// ---------------------------------------------------------------------------
// out[m,n] = A[m,:].Wo[n,:] + bo[n]  (fp32 out). m-fast grid.
// ---------------------------------------------------------------------------
__global__ __launch_bounds__(256, 4) void out_kernel(
    const short* __restrict__ A, const short* __restrict__ W,
    const float* __restrict__ bias, float* __restrict__ Y)
{
    const int m0 = blockIdx.x * 128;
    const int n0 = blockIdx.y * 128;

    __shared__ short At[128 * 64];
    __shared__ short Bt[128 * 64];

    floatx4 acc[4][4];
#pragma unroll
    for (int i = 0; i < 4; ++i)
#pragma unroll
        for (int j = 0; j < 4; ++j) acc[i][j] = (floatx4){0.f, 0.f, 0.f, 0.f};

    gemm_core(A + (size_t)m0 * E_DIM, E_DIM, W + (size_t)n0 * E_DIM, E_DIM,
              E_DIM, At, Bt, acc);

    const int lane = threadIdx.x & 63, wv = threadIdx.x >> 6;
    const int lm = lane & 15, lq = lane >> 4;
    const int wm = (wv & 1) * 64, wn = (wv >> 1) * 64;

#pragma unroll
    for (int j = 0; j < 4; ++j) {
        int n = n0 + wn + j * 16 + lm;
        float bv = bias[n];
#pragma unroll
        for (int i = 0; i < 4; ++i)
#pragma unroll
            for (int r = 0; r < 4; ++r) {
                int m = m0 + wm + i * 16 + lq * 4 + r;
                Y[(size_t)m * E_DIM + n] = acc[i][j][r] + bv;
            }
    }
}

// ---------------------------------------------------------------------------
extern "C" void kernel_launch(void* const* d_in, const int* in_sizes, int n_in,
                              void* d_out, int out_size, void* d_ws, size_t ws_size,
                              hipStream_t stream) {
    const float* value = (const float*)d_in[0];
    const float* key   = (const float*)d_in[1];
    const float* query = (const float*)d_in[2];
    const int*   mask  = (const int*)d_in[3];
    const float* Wv    = (const float*)d_in[4];
    const float* Wk    = (const float*)d_in[5];
    const float* Wq    = (const float*)d_in[6];
    const float* Wo    = (const float*)d_in[7];
    const float* bo    = (const float*)d_in[8];
    float* out = (float*)d_out;

    const size_t WN  = (size_t)E_DIM * E_DIM;
    const size_t ACT = (size_t)BATCH * S_LEN * E_DIM;

    short* Wb  = (short*)d_ws;
    short* xv  = Wb + 4 * WN;
    short* xk  = xv + ACT;
    short* xq  = xk + ACT;
    short* vt  = xq + ACT;
    short* kb  = vt + ACT;
    short* qb  = kb + ACT;
    float* rowsum = (float*)(qb + ACT);
    int*   nv  = (int*)(rowsum + (size_t)BATCH * S_LEN);
    int*   nvp = nv + BATCH;
    int*   jidx = (int*)qb;            // consumed by gather before proj writes qb
    short* P    = xv;                  // overlays dead xv/xk
    short* abuf = qb;                  // overlays dead qb

    // 6 dispatches total: prep fuses wconv+qconv+mask_scan+memset.
    prep<<<6424, 256, 0, stream>>>(Wv, Wk, Wq, Wo, query, mask,
                                   Wb, xq, rowsum, jidx, nv, nvp);

    gather_vk<<<dim3(512, 2, 8), 256, 0, stream>>>(value, key, jidx, nvp, xv, xk);

    proj_kernel<<<dim3(128, 6, 3), 256, 0, stream>>>(xv, xk, xq, Wb, nvp,
                                                     vt, kb, qb);

    score_kernel<<<dim3(16, 16, 8), 256, 0, stream>>>(qb, kb, nv, nvp, P, rowsum);

    pv_kernel<<<dim3(16, 6, 8), 256, 0, stream>>>(P, vt, rowsum, nvp, abuf);

    out_kernel<<<dim3(128, 6), 256, 0, stream>>>(abuf, Wb + 3 * WN, bo, out);
}

// Round 8
// 338.160 us; speedup vs baseline: 1.0926x; 1.0255x over previous
//
#include <hip/hip_runtime.h>
#include <hip/hip_bf16.h>
#include <stdint.h>

#define E_DIM 768
#define S_LEN 2048
#define BATCH 8

typedef __attribute__((ext_vector_type(8))) short short8;   // 8 x bf16 = 4 VGPRs
typedef __attribute__((ext_vector_type(4))) float floatx4;  // MFMA C/D
typedef long long fp8x8;                                    // 8 x fp8 = 2 VGPRs

__device__ __forceinline__ short f2bf(float f) {
    return __builtin_bit_cast(short, __float2bfloat16(f));
}

// fp32 -> OCP e4m3 byte via v_cvt_pk_fp8_f32 (gfx950 native OCP format,
// matches the fp8 MFMA operand encoding).
__device__ __forceinline__ uint8_t f2fp8(float f) {
    return (uint8_t)(__builtin_amdgcn_cvt_pk_fp8_f32(f, f, 0, false) & 0xff);
}

__device__ __forceinline__ floatx4 mfma16(short8 a, short8 b, floatx4 c) {
    return __builtin_amdgcn_mfma_f32_16x16x32_bf16(a, b, c, 0, 0, 0);
}

__device__ __forceinline__ floatx4 mfma8(fp8x8 a, fp8x8 b, floatx4 c) {
    return __builtin_amdgcn_mfma_f32_16x16x32_fp8_fp8(a, b, c, 0, 0, 0);
}

// async global->LDS, 16B per lane; LDS dst is wave-uniform base + lane*16,
// global src per-lane free -> XOR swizzle realized by permuting the SOURCE.
__device__ __forceinline__ void glds16(const short* g, short* l) {
    __builtin_amdgcn_global_load_lds(
        (const __attribute__((address_space(1))) void*)g,
        (__attribute__((address_space(3))) void*)l,
        16, 0, 0);
}
__device__ __forceinline__ void glds16b(const uint8_t* g, uint8_t* l) {
    __builtin_amdgcn_global_load_lds(
        (const __attribute__((address_space(1))) void*)g,
        (__attribute__((address_space(3))) void*)l,
        16, 0, 0);
}

// ---------------------------------------------------------------------------
// Shared GEMM core (bf16): C[128x128] += A[128xK] * B[128xK]^T.
// 256 threads = 4 waves (2x2), each wave 64x64 via 4x4 frags of 16x16x32.
// BK=64 single-buffered; XOR-swizzled staging -> conflict-free ds_read_b128.
//
// SESSION LEDGER (do not re-attempt):
//  R4  LDS-transpose epilogue         -> REGRESSED (347->381, +22MB fetch)
//  R5  256^2/8-wave/ring-4 vmcnt(8)   -> REGRESSED (346->446, 1 blk/CU)
//  R7  BK=32/ring-3/counted vmcnt(4)  -> REGRESSED (351->369, 2x barriers)
//  R8  2-wave/64x128 (acc[4][8])      -> REGRESSED (351->361, reg cliff)
//  R10 __launch_bounds__(256,4)       -> NEUTRAL (occ 17.7->20.6%, time flat:
//      structure is LDS-pipe+drain-bound at any occupancy >=3 blk/CU; keep
//      the bounds, they're harmless)
// Schedule + geometry FROZEN. R11: cut LDS BYTES via fp8 score path instead.
// (R11 first submission = broker infra failure, resubmitted unchanged.)
// ---------------------------------------------------------------------------
__device__ __forceinline__ void gemm_core(
    const short* __restrict__ Abase, size_t sA,
    const short* __restrict__ Bbase, size_t sB,
    int K,
    short* At, short* Bt,              // 128*64 shorts each (16KB)
    floatx4 acc[4][4])
{
    const int tid  = threadIdx.x;
    const int lane = tid & 63;
    const int wv   = tid >> 6;
    const int lm   = lane & 15, lq = lane >> 4;
    const int rl   = lane >> 3, sl = lane & 7;
    const int usw  = sl ^ rl;                   // swizzled source unit
    const int wm   = (wv & 1) * 64, wn = (wv >> 1) * 64;

    const short* ag = Abase + (size_t)(wv * 32 + rl) * sA + usw * 8;
    const short* bg = Bbase + (size_t)(wv * 32 + rl) * sB + usw * 8;
    short* al = At + wv * 4 * 512;
    short* bl = Bt + wv * 4 * 512;
    const size_t askip = 8 * sA, bskip = 8 * sB;

    for (int kt = 0; kt < K; kt += 64) {
#pragma unroll
        for (int c = 0; c < 4; ++c) glds16(ag + c * askip + kt, al + c * 512);
#pragma unroll
        for (int c = 0; c < 4; ++c) glds16(bg + c * bskip + kt, bl + c * 512);
        __syncthreads();

#pragma unroll
        for (int s = 0; s < 2; ++s) {
            const int u = s * 4 + lq;
            short8 af[4], bf[4];
#pragma unroll
            for (int i = 0; i < 4; ++i) {
                int r = wm + i * 16 + lm;
                af[i] = *(const short8*)&At[((r >> 3) * 64 + (r & 7) * 8 + (u ^ (r & 7))) * 8];
            }
#pragma unroll
            for (int j = 0; j < 4; ++j) {
                int r = wn + j * 16 + lm;
                bf[j] = *(const short8*)&Bt[((r >> 3) * 64 + (r & 7) * 8 + (u ^ (r & 7))) * 8];
            }
#pragma unroll
            for (int i = 0; i < 4; ++i)
#pragma unroll
                for (int j = 0; j < 4; ++j)
                    acc[i][j] = mfma16(af[i], bf[j], acc[i][j]);
        }
        __syncthreads();
    }
}

// ---------------------------------------------------------------------------
// fp8 GEMM core (score only): C[128x128] += A[128xK] * B[128xK]^T, A/B e4m3,
// strides in BYTES. Same 4-wave 2x2 / BK=64 / 2-barrier structure; tile is
// 128 rows x 64B (8KB) -> LDS bytes HALVE vs bf16 (48KB vs 96KB per
// block-K-step on the bound pipe), 4 glds vs 8 (cheaper drain).
// Layout: row-pair P at bytes [P*128,+128); logical slot X=(r&1)*4+g stored
// at 16B slot X^(P&7). Staging: lane l -> X=(l&7)^(l>>3),
// row = wv*32 + c*16 + (l>>3)*2 + (X>>2), src granule (X&3)*16 (R7-verified
// source-permute family). Read: 8B at P*128 + slot*16 + (u&1)*8.
// Verified inverse-consistent (row5/byte40 -> slot4@P2 -> lane20 round0).
// ---------------------------------------------------------------------------
__device__ __forceinline__ void gemm_core8(
    const uint8_t* __restrict__ Abase, size_t sA,
    const uint8_t* __restrict__ Bbase, size_t sB,
    int K,
    uint8_t* At, uint8_t* Bt,          // 8KB each
    floatx4 acc[4][4])
{
    const int tid  = threadIdx.x;
    const int lane = tid & 63;
    const int wv   = tid >> 6;
    const int lm   = lane & 15, lq = lane >> 4;
    const int rl   = lane >> 3, sl = lane & 7;
    const int X    = sl ^ rl;
    const int wm   = (wv & 1) * 64, wn = (wv >> 1) * 64;

    const int r0 = wv * 32 + rl * 2 + (X >> 2);
    const uint8_t* ag = Abase + (size_t)r0 * sA + (X & 3) * 16;
    const uint8_t* bg = Bbase + (size_t)r0 * sB + (X & 3) * 16;
    uint8_t* al = At + wv * 2048;
    uint8_t* bl = Bt + wv * 2048;
    const size_t a16 = (size_t)16 * sA, b16 = (size_t)16 * sB;

    const int gr_hi = lq >> 1;          // granule bit from lane
    const int hb    = (lq & 1) * 8;     // 8B half within 16B slot

    for (int kt = 0; kt < K; kt += 64) {
        glds16b(ag + kt, al);
        glds16b(ag + a16 + kt, al + 1024);
        glds16b(bg + kt, bl);
        glds16b(bg + b16 + kt, bl + 1024);
        __syncthreads();

#pragma unroll
        for (int s = 0; s < 2; ++s) {
            const int gr = s * 2 + gr_hi;       // granule 0..3
            fp8x8 af[4], bf[4];
#pragma unroll
            for (int i = 0; i < 4; ++i) {
                int r = wm + i * 16 + lm;
                int pr = r >> 1;
                int slot = (((r & 1) << 2) | gr) ^ (pr & 7);
                af[i] = *(const fp8x8*)&At[pr * 128 + slot * 16 + hb];
            }
#pragma unroll
            for (int j = 0; j < 4; ++j) {
                int r = wn + j * 16 + lm;
                int pr = r >> 1;
                int slot = (((r & 1) << 2) | gr) ^ (pr & 7);
                bf[j] = *(const fp8x8*)&Bt[pr * 128 + slot * 16 + hb];
            }
#pragma unroll
            for (int i = 0; i < 4; ++i)
#pragma unroll
                for (int j = 0; j < 4; ++j)
                    acc[i][j] = mfma8(af[i], bf[j], acc[i][j]);
        }
        __syncthreads();
    }
}

// ---------------------------------------------------------------------------
// prep: fused front-end. R11 change: Wq NO LONGER pre-scaled by 1/E (fp8
// score inputs must be ~N(0,1) to avoid e4m3 subnormals); the 1/E moves to
// score's epilogue as an fp32 multiply before exp (mathematically identical).
// ---------------------------------------------------------------------------
__global__ void prep(const float* __restrict__ Wv, const float* __restrict__ Wk,
                     const float* __restrict__ Wq, const float* __restrict__ Wo,
                     const float* __restrict__ query, const int* __restrict__ mask,
                     short* __restrict__ Wb, short* __restrict__ xq,
                     float* __restrict__ rowsum,
                     int* __restrict__ jidx, int* __restrict__ nv,
                     int* __restrict__ nvp)
{
    __shared__ int cnt[256];
    const int blk = blockIdx.x;
    const int t   = threadIdx.x;

    if (blk < 2304) {                       // ---- weight convert (no scale)
        const int z = blk / 576;
        const float* src = (z == 0) ? Wv : (z == 1) ? Wk : (z == 2) ? Wq : Wo;
        size_t i = ((size_t)(blk - z * 576) * 256 + t) * 4;
        float4 f = *(const float4*)(src + i);
        short4 h;
        h.x = f2bf(f.x); h.y = f2bf(f.y);
        h.z = f2bf(f.z); h.w = f2bf(f.w);
        *(short4*)(Wb + (size_t)z * E_DIM * E_DIM + i) = h;
    } else if (blk < 6400) {                // ---- query convert, 4 rows/block
        const int g0 = blk - 2304;          // 0..4095
        const size_t base = (size_t)g0 * 4 * E_DIM;
#pragma unroll
        for (int p = 0; p < 3; ++p) {
            size_t i = base + ((size_t)p * 256 + t) * 4;
            float4 f = *(const float4*)(query + i);
            short4 h;
            h.x = f2bf(f.x); h.y = f2bf(f.y); h.z = f2bf(f.z); h.w = f2bf(f.w);
            *(short4*)(xq + i) = h;
        }
    } else if (blk < 6416) {                // ---- rowsum zero
        const int g0 = blk - 6400;
        *(float4*)(rowsum + ((size_t)g0 * 256 + t) * 4) = (float4){0.f, 0.f, 0.f, 0.f};
    } else {                                // ---- mask compaction
        const int b = blk - 6416;
        int m[8];
        int c = 0;
#pragma unroll
        for (int k = 0; k < 8; ++k) {
            m[k] = mask[b * S_LEN + t * 8 + k];
            c += (m[k] != 0);
        }
        cnt[t] = c;
        __syncthreads();
        for (int off = 1; off < 256; off <<= 1) {
            int v = (t >= off) ? cnt[t - off] : 0;
            __syncthreads();
            cnt[t] += v;
            __syncthreads();
        }
        int pos = cnt[t] - c;
        const int total = cnt[255];
#pragma unroll
        for (int k = 0; k < 8; ++k)
            if (m[k] != 0) jidx[b * S_LEN + (pos++)] = t * 8 + k;
        __syncthreads();
        for (int i = total + t; i < S_LEN; i += 256) jidx[b * S_LEN + i] = 0;
        if (t == 0) {
            nv[b] = total;
            int p = (total + 127) & ~127;
            if (p < 128) p = 128;
            nvp[b] = p;
        }
    }
}

// ---------------------------------------------------------------------------
// gather+convert value/key rows through jidx (compacted). 4 rows/block.
// ---------------------------------------------------------------------------
__global__ void gather_vk(const float* __restrict__ v, const float* __restrict__ k,
                          const int* __restrict__ jidx, const int* __restrict__ nvp,
                          short* __restrict__ xv, short* __restrict__ xk) {
    const int z = blockIdx.y, b = blockIdx.z;
    const int r0 = blockIdx.x * 4;
    if (r0 >= nvp[b]) return;
    const float* src = (z == 0) ? v : k;
    short* dst = (z == 0) ? xv : xk;
    const int tid = threadIdx.x;
#pragma unroll
    for (int p = 0; p < 3; ++p) {
        int g   = p * 256 + tid;
        int row = r0 + g / 192;
        int c4  = (g % 192) * 4;
        int srow = jidx[b * S_LEN + row];
        float4 f = *(const float4*)(src + ((size_t)b * S_LEN + srow) * E_DIM + c4);
        short4 h;
        h.x = f2bf(f.x); h.y = f2bf(f.y); h.z = f2bf(f.z); h.w = f2bf(f.w);
        *(short4*)(dst + ((size_t)b * S_LEN + row) * E_DIM + c4) = h;
    }
}

// ---------------------------------------------------------------------------
// Projections. z==0: V -> vt bf16 (transposed); z==1: K -> kb8 fp8;
// z==2: Q -> qb8 fp8 (unscaled; ~N(0,1) is the e4m3 sweet spot).
// ---------------------------------------------------------------------------
__global__ __launch_bounds__(256, 4) void proj_kernel(
    const short* __restrict__ xv, const short* __restrict__ xk, const short* __restrict__ xq,
    const short* __restrict__ Wb, const int* __restrict__ nvp,
    short* __restrict__ vt, uint8_t* __restrict__ kb8, uint8_t* __restrict__ qb8)
{
    const int z  = blockIdx.z;
    const int mt = blockIdx.x;
    const int n0 = blockIdx.y * 128;

    int b = 0, lm0 = 0;
    const short* X;
    if (z == 2) {
        X = xq + (size_t)mt * 128 * E_DIM;
    } else {
        b   = mt >> 4;
        lm0 = (mt & 15) * 128;
        if (lm0 >= nvp[b]) return;
        X = ((z == 0) ? xv : xk) + ((size_t)b * S_LEN + lm0) * E_DIM;
    }
    const short* W = Wb + (size_t)z * E_DIM * E_DIM + (size_t)n0 * E_DIM;

    __shared__ short At[128 * 64];
    __shared__ short Bt[128 * 64];

    floatx4 acc[4][4];
#pragma unroll
    for (int i = 0; i < 4; ++i)
#pragma unroll
        for (int j = 0; j < 4; ++j) acc[i][j] = (floatx4){0.f, 0.f, 0.f, 0.f};

    gemm_core(X, E_DIM, W, E_DIM, E_DIM, At, Bt, acc);

    const int lane = threadIdx.x & 63, wv = threadIdx.x >> 6;
    const int lm = lane & 15, lq = lane >> 4;
    const int wm = (wv & 1) * 64, wn = (wv >> 1) * 64;

    if (z == 0) {        // vt[b][n][i] bf16
#pragma unroll
        for (int i = 0; i < 4; ++i)
#pragma unroll
            for (int r = 0; r < 4; ++r) {
                int li = lm0 + wm + i * 16 + lq * 4 + r;
#pragma unroll
                for (int j = 0; j < 4; ++j) {
                    int n = n0 + wn + j * 16 + lm;
                    vt[((size_t)b * E_DIM + n) * S_LEN + li] = f2bf(acc[i][j][r]);
                }
            }
    } else if (z == 1) { // kb8[b][i][e] fp8
#pragma unroll
        for (int i = 0; i < 4; ++i)
#pragma unroll
            for (int r = 0; r < 4; ++r) {
                int li = lm0 + wm + i * 16 + lq * 4 + r;
#pragma unroll
                for (int j = 0; j < 4; ++j) {
                    int n = n0 + wn + j * 16 + lm;
                    kb8[((size_t)b * S_LEN + li) * E_DIM + n] = f2fp8(acc[i][j][r]);
                }
            }
    } else {             // qb8[m][e] fp8
#pragma unroll
        for (int i = 0; i < 4; ++i)
#pragma unroll
            for (int r = 0; r < 4; ++r) {
                int m = mt * 128 + wm + i * 16 + lq * 4 + r;
#pragma unroll
                for (int j = 0; j < 4; ++j) {
                    int n = n0 + wn + j * 16 + lm;
                    qb8[(size_t)m * E_DIM + n] = f2fp8(acc[i][j][r]);
                }
            }
    }
}

// ---------------------------------------------------------------------------
// S = (q.k^T)/E over compacted columns via fp8 MFMA; fused exp + rowsum.
// 1/E applied in fp32 AFTER the accumulation (was pre-folded into Wq).
// ---------------------------------------------------------------------------
__global__ __launch_bounds__(256, 4) void score_kernel(
    const uint8_t* __restrict__ qb8, const uint8_t* __restrict__ kb8,
    const int* __restrict__ nv, const int* __restrict__ nvp,
    short* __restrict__ P, float* __restrict__ rowsum)
{
    const int b  = blockIdx.z;
    const int m0 = blockIdx.x * 128;
    const int n0 = blockIdx.y * 128;
    if (n0 >= nvp[b]) return;

    __shared__ __align__(16) uint8_t At8[128 * 64];
    __shared__ __align__(16) uint8_t Bt8[128 * 64];

    floatx4 acc[4][4];
#pragma unroll
    for (int i = 0; i < 4; ++i)
#pragma unroll
        for (int j = 0; j < 4; ++j) acc[i][j] = (floatx4){0.f, 0.f, 0.f, 0.f};

    gemm_core8(qb8 + ((size_t)b * S_LEN + m0) * E_DIM, E_DIM,
               kb8 + ((size_t)b * S_LEN + n0) * E_DIM, E_DIM, E_DIM, At8, Bt8, acc);

    const int lane = threadIdx.x & 63, wv = threadIdx.x >> 6;
    const int lm = lane & 15, lq = lane >> 4;
    const int wm = (wv & 1) * 64, wn = (wv >> 1) * 64;
    const int nvb = nv[b];
    const float inv_e = 1.0f / (float)E_DIM;

    float rsum[4][4];
#pragma unroll
    for (int i = 0; i < 4; ++i)
#pragma unroll
        for (int r = 0; r < 4; ++r) rsum[i][r] = 0.f;

    const size_t Pbb = (size_t)b * S_LEN * S_LEN;
#pragma unroll
    for (int j = 0; j < 4; ++j) {
        int n = n0 + wn + j * 16 + lm;
        bool valid = n < nvb;
#pragma unroll
        for (int i = 0; i < 4; ++i) {
            int mbase = m0 + wm + i * 16 + lq * 4;
#pragma unroll
            for (int r = 0; r < 4; ++r) {
                float p = valid ? __expf(acc[i][j][r] * inv_e) : 0.0f;
                rsum[i][r] += p;
                P[Pbb + (size_t)(mbase + r) * S_LEN + n] = f2bf(p);
            }
        }
    }
#pragma unroll
    for (int i = 0; i < 4; ++i)
#pragma unroll
        for (int r = 0; r < 4; ++r) {
            float v = rsum[i][r];
            v += __shfl_xor(v, 1);
            v += __shfl_xor(v, 2);
            v += __shfl_xor(v, 4);
            v += __shfl_xor(v, 8);
            if (lm == 0)
                atomicAdd(&rowsum[b * S_LEN + m0 + wm + i * 16 + lq * 4 + r], v);
        }
}

// ---------------------------------------------------------------------------
// O = (P.V)/rowsum over compacted K (nvp[b]) -> abuf bf16.
// ---------------------------------------------------------------------------
__global__ __launch_bounds__(256, 4) void pv_kernel(
    const short* __restrict__ P, const short* __restrict__ vt,
    const float* __restrict__ rowsum, const int* __restrict__ nvp,
    short* __restrict__ abuf)
{
    const int b  = blockIdx.z;
    const int m0 = blockIdx.x * 128;
    const int n0 = blockIdx.y * 128;

    __shared__ short At[128 * 64];
    __shared__ short Bt[128 * 64];

    floatx4 acc[4][4];
#pragma unroll
    for (int i = 0; i < 4; ++i)
#pragma unroll
        for (int j = 0; j < 4; ++j) acc[i][j] = (floatx4){0.f, 0.f, 0.f, 0.f};

    gemm_core(P + (size_t)b * S_LEN * S_LEN + (size_t)m0 * S_LEN, S_LEN,
              vt + ((size_t)b * E_DIM + n0) * S_LEN, S_LEN, nvp[b], At, Bt, acc);

    const int lane = threadIdx.x & 63, wv = threadIdx.x >> 6;
    const int lm = lane & 15, lq = lane >> 4;
    const int wm = (wv & 1) * 64, wn = (wv >> 1) * 64;

#pragma unroll
    for (int i = 0; i < 4; ++i) {
        int mbase = m0 + wm + i * 16 + lq * 4;
#pragma unroll
        for (int r = 0; r < 4; ++r) {
            float inv = 1.0f / rowsum[b * S_LEN + mbase + r];
            size_t ob = ((size_t)b * S_LEN + mbase + r) * E_DIM;
#pragma unroll
            for (int j = 0; j < 4; ++j) {
                int n = n0 + wn + j * 16 + lm;
                abuf[ob + n] = f2bf(acc[i][j][r] * inv);
            }
        }
    }
}

// ---------------------------------------------------------------------------
// out[m,n] = A[m,:].Wo[n,:] + bo[n]  (fp32 out). m-fast grid.
// ---------------------------------------------------------------------------
__global__ __launch_bounds__(256, 4) void out_kernel(
    const short* __restrict__ A, const short* __restrict__ W,
    const float* __restrict__ bias, float* __restrict__ Y)
{
    const int m0 = blockIdx.x * 128;
    const int n0 = blockIdx.y * 128;

    __shared__ short At[128 * 64];
    __shared__ short Bt[128 * 64];

    floatx4 acc[4][4];
#pragma unroll
    for (int i = 0; i < 4; ++i)
#pragma unroll
        for (int j = 0; j < 4; ++j) acc[i][j] = (floatx4){0.f, 0.f, 0.f, 0.f};

    gemm_core(A + (size_t)m0 * E_DIM, E_DIM, W + (size_t)n0 * E_DIM, E_DIM,
              E_DIM, At, Bt, acc);

    const int lane = threadIdx.x & 63, wv = threadIdx.x >> 6;
    const int lm = lane & 15, lq = lane >> 4;
    const int wm = (wv & 1) * 64, wn = (wv >> 1) * 64;

#pragma unroll
    for (int j = 0; j < 4; ++j) {
        int n = n0 + wn + j * 16 + lm;
        float bv = bias[n];
#pragma unroll
        for (int i = 0; i < 4; ++i)
#pragma unroll
            for (int r = 0; r < 4; ++r) {
                int m = m0 + wm + i * 16 + lq * 4 + r;
                Y[(size_t)m * E_DIM + n] = acc[i][j][r] + bv;
            }
    }
}

// ---------------------------------------------------------------------------
extern "C" void kernel_launch(void* const* d_in, const int* in_sizes, int n_in,
                              void* d_out, int out_size, void* d_ws, size_t ws_size,
                              hipStream_t stream) {
    const float* value = (const float*)d_in[0];
    const float* key   = (const float*)d_in[1];
    const float* query = (const float*)d_in[2];
    const int*   mask  = (const int*)d_in[3];
    const float* Wv    = (const float*)d_in[4];
    const float* Wk    = (const float*)d_in[5];
    const float* Wq    = (const float*)d_in[6];
    const float* Wo    = (const float*)d_in[7];
    const float* bo    = (const float*)d_in[8];
    float* out = (float*)d_out;

    const size_t WN  = (size_t)E_DIM * E_DIM;
    const size_t ACT = (size_t)BATCH * S_LEN * E_DIM;

    short* Wb  = (short*)d_ws;
    short* xv  = Wb + 4 * WN;
    short* xk  = xv + ACT;
    short* xq  = xk + ACT;
    short* vt  = xq + ACT;
    short* kb  = vt + ACT;
    short* qb  = kb + ACT;
    float* rowsum = (float*)(qb + ACT);
    int*   nv  = (int*)(rowsum + (size_t)BATCH * S_LEN);
    int*   nvp = nv + BATCH;
    int*   jidx = (int*)qb;            // consumed by gather before proj writes qb
    short* P    = xv;                  // overlays dead xv/xk
    short* abuf = qb;                  // overlays dead qb (qb8 dead after score)
    uint8_t* kb8 = (uint8_t*)kb;       // fp8 views of the kb/qb slots
    uint8_t* qb8 = (uint8_t*)qb;

    // 6 dispatches total: prep fuses wconv+qconv+mask_scan+memset.
    prep<<<6424, 256, 0, stream>>>(Wv, Wk, Wq, Wo, query, mask,
                                   Wb, xq, rowsum, jidx, nv, nvp);

    gather_vk<<<dim3(512, 2, 8), 256, 0, stream>>>(value, key, jidx, nvp, xv, xk);

    proj_kernel<<<dim3(128, 6, 3), 256, 0, stream>>>(xv, xk, xq, Wb, nvp,
                                                     vt, kb8, qb8);

    score_kernel<<<dim3(16, 16, 8), 256, 0, stream>>>(qb8, kb8, nv, nvp, P, rowsum);

    pv_kernel<<<dim3(16, 6, 8), 256, 0, stream>>>(P, vt, rowsum, nvp, abuf);

    out_kernel<<<dim3(128, 6), 256, 0, stream>>>(abuf, Wb + 3 * WN, bo, out);
}